// Round 1
// baseline (1917.589 us; speedup 1.0000x reference)
//
#include <hip/hip_runtime.h>

// DynamicGCN: B=16 N=512 T=24 D=E=H=64
// Per (b,t): E1=XW1+b1, E2=XW2+b2, S=relu(E1 E2^T), A=softmax rows, h=AX, out=relu(hW+b)
// Fused single kernel, flash-style online softmax, fp32 (correctness baseline).

#define B_ 16
#define N_ 512
#define T_ 24
#define D_ 64
#define E_ 64
#define H_ 64
#define TILE 64
#define NT (N_/TILE)   // 8 j-tiles
#define LP 68          // LDS row stride (floats): 16B-aligned, bank-friendly

__global__ __launch_bounds__(256, 2)
void gcn_fused(const float* __restrict__ x,
               const float* __restrict__ W1, const float* __restrict__ b1,
               const float* __restrict__ W2, const float* __restrict__ b2,
               const float* __restrict__ Wf, const float* __restrict__ bf,
               float* __restrict__ out)
{
    __shared__ __align__(16) float E1s[TILE*LP];
    __shared__ __align__(16) float E2s[TILE*LP];   // doubles as P-tile buffer
    __shared__ __align__(16) float Xs [TILE*LP];   // doubles as h buffer at epilogue

    const int tid  = threadIdx.x;
    const int lane = tid & 63;
    const int w    = tid >> 6;          // wave 0..3; wave owns 16 query rows
    const int bid  = blockIdx.x;
    const int tile = bid & (NT-1);      // row-tile of this block
    const int bt   = bid >> 3;
    const int b    = bt / T_;
    const int t    = bt - b*T_;
    const int r0   = tile * TILE;

    const size_t rstride = (size_t)T_*D_;           // row stride of x (and out, D_==H_)
    const float* xbt = x + ((size_t)b*N_*T_ + t)*D_;  // x[b, i, t, :] = xbt + i*rstride

    // ---------------- prologue ----------------
    const float bias1 = b1[lane];
    const float bias2 = b2[lane];

    float wcol[64];                      // W1 col `lane`, later W2 col, later Wf col
    #pragma unroll
    for (int k = 0; k < 64; ++k) wcol[k] = W1[k*E_ + lane];

    // stage own X tile (rows r0..r0+63)
    #pragma unroll
    for (int it = 0; it < 4; ++it) {
        int idx = tid + it*256;          // float4 index
        int row = idx >> 4;
        int c4  = idx & 15;
        float4 v = *(const float4*)(xbt + (size_t)(r0+row)*rstride + c4*4);
        *(float4*)&Xs[row*LP + c4*4] = v;
    }
    __syncthreads();

    // E1 for own rows: E1s[16w+j][lane]  (read later only by own wave -> no extra barrier)
    #pragma unroll
    for (int j = 0; j < 16; ++j) {
        float a = bias1;
        #pragma unroll
        for (int kb = 0; kb < 16; ++kb) {
            float4 xv = *(const float4*)&Xs[(16*w + j)*LP + kb*4];   // wave-uniform
            a += xv.x*wcol[4*kb+0] + xv.y*wcol[4*kb+1]
               + xv.z*wcol[4*kb+2] + xv.w*wcol[4*kb+3];
        }
        E1s[(16*w + j)*LP + lane] = a;
    }

    // switch wcol -> W2 column
    #pragma unroll
    for (int k = 0; k < 64; ++k) wcol[k] = W2[k*E_ + lane];

    float s[16], O[16], m[16], lsum[16];
    #pragma unroll
    for (int r = 0; r < 16; ++r) { O[r] = 0.f; m[r] = 0.f; lsum[r] = 0.f; }
    float col64[64];                     // time-shared: e2-row during S, x-column during PV

    // ---------------- j-tile loop ----------------
    for (int jt = 0; jt < NT; ++jt) {
        __syncthreads();                 // B1: Xs/E2s free to overwrite

        // stage X j-tile
        #pragma unroll
        for (int it = 0; it < 4; ++it) {
            int idx = tid + it*256;
            int row = idx >> 4;
            int c4  = idx & 15;
            float4 v = *(const float4*)(xbt + (size_t)(jt*TILE+row)*rstride + c4*4);
            *(float4*)&Xs[row*LP + c4*4] = v;
        }
        __syncthreads();                 // B2: Xs ready

        // E2 j-tile: rows 16w..16w+15, col `lane`
        #pragma unroll
        for (int j = 0; j < 16; ++j) {
            float a = bias2;
            #pragma unroll
            for (int kb = 0; kb < 16; ++kb) {
                float4 xv = *(const float4*)&Xs[(16*w + j)*LP + kb*4];  // uniform
                a += xv.x*wcol[4*kb+0] + xv.y*wcol[4*kb+1]
                   + xv.z*wcol[4*kb+2] + xv.w*wcol[4*kb+3];
            }
            E2s[(16*w + j)*LP + lane] = a;
        }
        __syncthreads();                 // B3: E2s ready

        // e2-row for this lane's score column
        #pragma unroll
        for (int kb = 0; kb < 16; ++kb) {
            float4 v = *(const float4*)&E2s[lane*LP + kb*4];
            col64[4*kb+0]=v.x; col64[4*kb+1]=v.y; col64[4*kb+2]=v.z; col64[4*kb+3]=v.w;
        }

        // S = relu(E1 . e2row)
        #pragma unroll
        for (int r = 0; r < 16; ++r) {
            float a = 0.f;
            #pragma unroll
            for (int eb = 0; eb < 16; ++eb) {
                float4 ev = *(const float4*)&E1s[(16*w + r)*LP + eb*4];  // uniform
                a += ev.x*col64[4*eb+0] + ev.y*col64[4*eb+1]
                   + ev.z*col64[4*eb+2] + ev.w*col64[4*eb+3];
            }
            s[r] = fmaxf(a, 0.f);
        }

        // online softmax update (row r lives across the 64 lanes of this wave)
        #pragma unroll
        for (int r = 0; r < 16; ++r) {
            float tm = s[r];
            #pragma unroll
            for (int off = 32; off > 0; off >>= 1)
                tm = fmaxf(tm, __shfl_xor(tm, off, 64));
            float mn = fmaxf(m[r], tm);          // m starts at 0: valid, relu scores >= 0
            float p  = __expf(s[r] - mn);
            float ps = p;
            #pragma unroll
            for (int off = 32; off > 0; off >>= 1)
                ps += __shfl_xor(ps, off, 64);
            float sc = __expf(m[r] - mn);
            O[r]    *= sc;
            lsum[r]  = lsum[r]*sc + ps;
            m[r]     = mn;
            s[r]     = p;
        }

        __syncthreads();                 // B4: all waves done reading E2s rows

        // write P over E2s (own rows only; read back by own wave only)
        #pragma unroll
        for (int r = 0; r < 16; ++r)
            E2s[(16*w + r)*LP + lane] = s[r];

        // x-column for this lane's output dim
        #pragma unroll
        for (int j = 0; j < 64; ++j)
            col64[j] = Xs[j*LP + lane];

        // PV: O[r] += sum_j P[r][j] * X[j][lane]
        #pragma unroll
        for (int r = 0; r < 16; ++r) {
            float a = O[r];
            #pragma unroll
            for (int jb = 0; jb < 16; ++jb) {
                float4 pv = *(const float4*)&E2s[(16*w + r)*LP + jb*4];  // uniform, own rows
                a += pv.x*col64[4*jb+0] + pv.y*col64[4*jb+1]
                   + pv.z*col64[4*jb+2] + pv.w*col64[4*jb+3];
            }
            O[r] = a;
        }
    }

    // ---------------- epilogue: h = O/lsum, out = relu(h W + b) ----------------
    __syncthreads();                     // PV reads of Xs/E2s done
    #pragma unroll
    for (int r = 0; r < 16; ++r)
        Xs[(16*w + r)*LP + lane] = O[r] / lsum[r];   // h tile

    #pragma unroll
    for (int k = 0; k < 64; ++k) wcol[k] = Wf[k*H_ + lane];
    const float biasf = bf[lane];
    __syncthreads();                     // h ready

    float* obt = out + ((size_t)b*N_*T_ + t)*H_;
    #pragma unroll
    for (int r = 0; r < 16; ++r) {
        float a = biasf;
        #pragma unroll
        for (int db = 0; db < 16; ++db) {
            float4 hv = *(const float4*)&Xs[(16*w + r)*LP + db*4];       // uniform
            a += hv.x*wcol[4*db+0] + hv.y*wcol[4*db+1]
               + hv.z*wcol[4*db+2] + hv.w*wcol[4*db+3];
        }
        obt[(size_t)(r0 + 16*w + r)*rstride + lane] = fmaxf(a, 0.f);
    }
}

extern "C" void kernel_launch(void* const* d_in, const int* in_sizes, int n_in,
                              void* d_out, int out_size, void* d_ws, size_t ws_size,
                              hipStream_t stream) {
    const float* x  = (const float*)d_in[0];
    const float* W1 = (const float*)d_in[1];
    const float* b1 = (const float*)d_in[2];
    const float* W2 = (const float*)d_in[3];
    const float* b2 = (const float*)d_in[4];
    const float* Wf = (const float*)d_in[5];
    const float* bf = (const float*)d_in[6];
    float* out = (float*)d_out;

    dim3 grid(B_ * T_ * NT);             // 3072 blocks, one 64-row tile of one (b,t) each
    gcn_fused<<<grid, dim3(256), 0, stream>>>(x, W1, b1, W2, b2, Wf, bf, out);
}

// Round 3
// 310.201 us; speedup vs baseline: 6.1818x; 6.1818x over previous
//
#include <hip/hip_runtime.h>

// DynamicGCN B=16 N=512 T=24 D=E=H=64 — full-MFMA transpose-chain, split-bf16.
// Per (b,t): E1=XW1+b1, E2=XW2+b2, S=relu(E1 E2^T), A=softmax(S), h=AX, out=relu(hW+b)
// R3: PV B-operand from a d-major XT LDS plane via plain ds_read_b64 fragments
//     (no inline asm / no ds_read_b64_tr_b16) — bisects R2's failure.

#define B_ 16
#define N_ 512
#define T_ 24
#define D_ 64
#define NT 8

typedef __attribute__((ext_vector_type(8))) short short8;
typedef __attribute__((ext_vector_type(4))) unsigned short u16x4;
typedef __attribute__((ext_vector_type(4))) float f32x4;

#define MFMA_BF16 __builtin_amdgcn_mfma_f32_16x16x32_bf16
#define WFIDX(q, cd, s, l) (((((q)*2 + (cd))*2 + (s))*64 + (l))*8)

__device__ __forceinline__ unsigned short f2bf(float f) {
    unsigned u = __float_as_uint(f);
    return (unsigned short)((u + 0x7FFFu + ((u >> 16) & 1u)) >> 16);
}
__device__ __forceinline__ float bf2f(unsigned short h) {
    return __uint_as_float(((unsigned)h) << 16);
}
// X-tile LDS layout (u16 element index in a 4352-elem plane):
// addr(j,d) = (d>>4)*1088 + (j>>2)*68 + (j&3)*16 + (d&15)
__device__ __forceinline__ int XIDX(int j, int d) {
    return (d >> 4) * 1088 + (j >> 2) * 68 + ((j & 3) << 4) + (d & 15);
}
// d-major twin: XT[d][j] with the same structure (rows=d, cols=j)
__device__ __forceinline__ int XTIDX(int d, int j) {
    return (j >> 4) * 1088 + (d >> 2) * 68 + ((d & 3) << 4) + (j & 15);
}

// stage one 64x64 f32 tile -> bf16 hi/lo planes in XIDX layout (+ optional d-major hi twin)
__device__ __forceinline__ void stage_x(unsigned short* xb, unsigned short* xt,
                                        const float* src, int tid) {
    const int rs = T_ * D_;
    #pragma unroll
    for (int it = 0; it < 4; ++it) {
        int idx = tid + it * 256;
        int j = idx >> 4, d0 = (idx & 15) << 2;
        f32x4 v = *(const f32x4*)(src + (size_t)j * rs + d0);
        u16x4 hv, lv;
        #pragma unroll
        for (int k = 0; k < 4; ++k) {
            unsigned short h = f2bf(v[k]);
            hv[k] = h;
            lv[k] = f2bf(v[k] - bf2f(h));
        }
        int o = XIDX(j, d0);
        *(u16x4*)&xb[o] = hv;
        *(u16x4*)&xb[o + 4352] = lv;
        if (xt) {
            #pragma unroll
            for (int k = 0; k < 4; ++k)
                xt[XTIDX(d0 + k, j)] = hv[k];
        }
    }
}

// gather MFMA operand frags of a 64x64 row-major weight (global) into LDS,
// hi/lo split: element W[32*cd + lam(g,jj)][16*q + (lane&15)],
// lam(g,jj) = 16*(jj>=4) + 4*g + (jj&3)
__device__ __forceinline__ void gather_wfrag(unsigned short* wf, const float* Wg, int tid) {
    int lane = tid & 63, w = tid >> 6;
    #pragma unroll
    for (int k = 0; k < 2; ++k) {
        int pair = w * 2 + k;          // 4 waves x 2 = all 8 (q,cd) pairs
        int q = pair >> 1, cd = pair & 1;
        int col = q * 16 + (lane & 15);
        short8 hf, lf;
        #pragma unroll
        for (int jj = 0; jj < 8; ++jj) {
            int row = cd * 32 + ((jj >> 2) << 4) + ((lane >> 4) << 2) + (jj & 3);
            float v = Wg[row * 64 + col];
            unsigned short h = f2bf(v);
            hf[jj] = (short)h;
            lf[jj] = (short)f2bf(v - bf2f(h));
        }
        *(short8*)&wf[WFIDX(q, cd, 0, lane)] = hf;
        *(short8*)&wf[WFIDX(q, cd, 1, lane)] = lf;
    }
}

// row-pattern operand frag: row fixed per lane, slots jj -> col = 32*cd + lam(g,jj)
__device__ __forceinline__ short8 xfrag(const unsigned short* xb, int row, int cd, int g) {
    u16x4 a = *(const u16x4*)&xb[XIDX(row, cd * 32 + (g << 2))];
    u16x4 b = *(const u16x4*)&xb[XIDX(row, cd * 32 + 16 + (g << 2))];
    short8 r;
    r[0] = (short)a[0]; r[1] = (short)a[1]; r[2] = (short)a[2]; r[3] = (short)a[3];
    r[4] = (short)b[0]; r[5] = (short)b[1]; r[6] = (short)b[2]; r[7] = (short)b[3];
    return r;
}

__global__ __launch_bounds__(256, 2)
void gcn_mfma(const float* __restrict__ x,
              const float* __restrict__ W1, const float* __restrict__ b1,
              const float* __restrict__ W2, const float* __restrict__ b2,
              const float* __restrict__ Wo, const float* __restrict__ bo,
              float* __restrict__ out)
{
    // S1(17408B): Xq -> W2frags -> h ; S2(17408B): W1frags -> Xj -> Wofrags ;
    // XT(8704B): d-major hi twin of Xj ; SH(16384B): E2T frag share ; biases 3*256B
    __shared__ __align__(16) char smem[60672];
    unsigned short* S1 = (unsigned short*)smem;
    unsigned short* S2 = (unsigned short*)(smem + 17408);
    unsigned short* XT = (unsigned short*)(smem + 34816);
    unsigned short* SH = (unsigned short*)(smem + 43520);
    float* b1s = (float*)(smem + 59904);
    float* b2s = (float*)(smem + 60160);
    float* bos = (float*)(smem + 60416);

    const int tid = threadIdx.x;
    const int lane = tid & 63;
    const int w = tid >> 6;
    const int g = lane >> 4;
    const int li = lane & 15;

    const int bid = blockIdx.x;
    const int tile = bid & (NT - 1);
    const int bt = bid >> 3;
    const int b = bt / T_;
    const int t = bt - b * T_;
    const int r0 = tile * 64;

    const size_t rstride = (size_t)T_ * D_;
    const float* xbt = x + ((size_t)b * N_ * T_ + t) * D_;

    if (tid < 64) b1s[tid] = b1[tid];
    else if (tid < 128) b2s[tid - 64] = b2[tid - 64];
    else if (tid < 192) bos[tid - 128] = bo[tid - 128];

    gather_wfrag(S2, W1, tid);                              // W1 frags
    stage_x(S1, nullptr, xbt + (size_t)r0 * rstride, tid);  // query X tile
    __syncthreads();

    // ---- E1T = W1^T Xq^T (+b1): tiles (q=e16, i16=wave) ----
    f32x4 eacc[4];
    #pragma unroll
    for (int q = 0; q < 4; ++q) eacc[q] = (f32x4){0.f, 0.f, 0.f, 0.f};
    const int orow = w * 16 + li;
    #pragma unroll
    for (int cd = 0; cd < 2; ++cd) {
        short8 xh = xfrag(S1, orow, cd, g);
        short8 xl = xfrag(S1 + 4352, orow, cd, g);
        #pragma unroll
        for (int q = 0; q < 4; ++q) {
            short8 wh = *(const short8*)&S2[WFIDX(q, cd, 0, lane)];
            short8 wl = *(const short8*)&S2[WFIDX(q, cd, 1, lane)];
            eacc[q] = MFMA_BF16(wh, xh, eacc[q], 0, 0, 0);
            eacc[q] = MFMA_BF16(wh, xl, eacc[q], 0, 0, 0);
            eacc[q] = MFMA_BF16(wl, xh, eacc[q], 0, 0, 0);
        }
    }
    short8 e1h[2], e1l[2];
    #pragma unroll
    for (int q = 0; q < 4; ++q) {
        #pragma unroll
        for (int r = 0; r < 4; ++r) eacc[q][r] += b1s[q * 16 + g * 4 + r];
    }
    #pragma unroll
    for (int c = 0; c < 2; ++c) {
        #pragma unroll
        for (int jj = 0; jj < 8; ++jj) {
            float v = eacc[c * 2 + (jj >> 2)][jj & 3];
            unsigned short h = f2bf(v);
            e1h[c][jj] = (short)h;
            e1l[c][jj] = (short)f2bf(v - bf2f(h));
        }
    }
    __syncthreads();
    gather_wfrag(S1, W2, tid);                       // W2 frags (S1 free now)

    f32x4 hacc[4];
    #pragma unroll
    for (int n = 0; n < 4; ++n) hacc[n] = (f32x4){0.f, 0.f, 0.f, 0.f};
    float mrun = 0.f, lsum = 0.f;

    #pragma unroll 1
    for (int jt8 = 0; jt8 < NT; ++jt8) {
        __syncthreads();
        stage_x(S2, XT, xbt + (size_t)(jt8 * 64) * rstride, tid);
        __syncthreads();

        // ---- E2T own j16 (tiles q=e16, j16=w), share as ST A-frags ----
        f32x4 e2[4];
        #pragma unroll
        for (int q = 0; q < 4; ++q) e2[q] = (f32x4){0.f, 0.f, 0.f, 0.f};
        #pragma unroll
        for (int cd = 0; cd < 2; ++cd) {
            short8 xh = xfrag(S2, orow, cd, g);
            short8 xl = xfrag(S2 + 4352, orow, cd, g);
            #pragma unroll
            for (int q = 0; q < 4; ++q) {
                short8 wh = *(const short8*)&S1[WFIDX(q, cd, 0, lane)];
                short8 wl = *(const short8*)&S1[WFIDX(q, cd, 1, lane)];
                e2[q] = MFMA_BF16(wh, xh, e2[q], 0, 0, 0);
                e2[q] = MFMA_BF16(wh, xl, e2[q], 0, 0, 0);
                e2[q] = MFMA_BF16(wl, xh, e2[q], 0, 0, 0);
            }
        }
        #pragma unroll
        for (int q = 0; q < 4; ++q) {
            #pragma unroll
            for (int r = 0; r < 4; ++r) e2[q][r] += b2s[q * 16 + g * 4 + r];
        }
        #pragma unroll
        for (int c = 0; c < 2; ++c) {
            short8 fh, fl;
            #pragma unroll
            for (int jj = 0; jj < 8; ++jj) {
                float v = e2[c * 2 + (jj >> 2)][jj & 3];
                unsigned short h = f2bf(v);
                fh[jj] = (short)h;
                fl[jj] = (short)f2bf(v - bf2f(h));
            }
            *(short8*)&SH[WFIDX(w, c, 0, lane)] = fh;
            *(short8*)&SH[WFIDX(w, c, 1, lane)] = fl;
        }
        __syncthreads();

        // ---- ST = E2 E1^T (16j x 16i tiles), relu, online softmax ----
        f32x4 st[4];
        #pragma unroll
        for (int jt = 0; jt < 4; ++jt) st[jt] = (f32x4){0.f, 0.f, 0.f, 0.f};
        #pragma unroll
        for (int jt = 0; jt < 4; ++jt) {
            #pragma unroll
            for (int c = 0; c < 2; ++c) {
                short8 ah = *(const short8*)&SH[WFIDX(jt, c, 0, lane)];
                short8 al = *(const short8*)&SH[WFIDX(jt, c, 1, lane)];
                st[jt] = MFMA_BF16(ah, e1h[c], st[jt], 0, 0, 0);
                st[jt] = MFMA_BF16(ah, e1l[c], st[jt], 0, 0, 0);
                st[jt] = MFMA_BF16(al, e1h[c], st[jt], 0, 0, 0);
            }
        }
        float tm = 0.f;
        #pragma unroll
        for (int jt = 0; jt < 4; ++jt) {
            #pragma unroll
            for (int r = 0; r < 4; ++r) {
                float s = fmaxf(st[jt][r], 0.f);
                st[jt][r] = s;
                tm = fmaxf(tm, s);
            }
        }
        tm = fmaxf(tm, __shfl_xor(tm, 16));
        tm = fmaxf(tm, __shfl_xor(tm, 32));
        float mn = fmaxf(mrun, tm);
        float corr = __expf(mrun - mn);
        float ps = 0.f;
        #pragma unroll
        for (int jt = 0; jt < 4; ++jt) {
            #pragma unroll
            for (int r = 0; r < 4; ++r) {
                float p = __expf(st[jt][r] - mn);
                st[jt][r] = p;
                ps += p;
            }
        }
        ps += __shfl_xor(ps, 16);
        ps += __shfl_xor(ps, 32);
        lsum = lsum * corr + ps;
        mrun = mn;
        float sc0 = __shfl(corr, g * 4 + 0);
        float sc1 = __shfl(corr, g * 4 + 1);
        float sc2 = __shfl(corr, g * 4 + 2);
        float sc3 = __shfl(corr, g * 4 + 3);
        #pragma unroll
        for (int n = 0; n < 4; ++n) {
            hacc[n][0] *= sc0; hacc[n][1] *= sc1; hacc[n][2] *= sc2; hacc[n][3] *= sc3;
        }

        // ---- PV: h += P X  (A = P frags from regs, B = row-frags of d-major XT) ----
        #pragma unroll
        for (int c = 0; c < 2; ++c) {
            short8 pa;
            #pragma unroll
            for (int jj = 0; jj < 8; ++jj)
                pa[jj] = (short)f2bf(st[c * 2 + (jj >> 2)][jj & 3]);
            #pragma unroll
            for (int n = 0; n < 4; ++n) {
                short8 xb = xfrag(XT, n * 16 + li, c, g);   // XT[d=16n+li][j-slots]
                hacc[n] = MFMA_BF16(pa, xb, hacc[n], 0, 0, 0);
            }
        }
    }

    // ---- epilogue: h /= lsum -> LDS (XIDX layout), out = relu(h Wo + bo) ----
    float linv = 1.0f / lsum;
    float l0 = __shfl(linv, g * 4 + 0);
    float l1 = __shfl(linv, g * 4 + 1);
    float l2 = __shfl(linv, g * 4 + 2);
    float l3 = __shfl(linv, g * 4 + 3);
    __syncthreads();
    #pragma unroll
    for (int n = 0; n < 4; ++n) {
        float lr[4] = {l0, l1, l2, l3};
        #pragma unroll
        for (int r = 0; r < 4; ++r) {
            float v = hacc[n][r] * lr[r];
            unsigned short h = f2bf(v);
            int o = XIDX(w * 16 + g * 4 + r, n * 16 + li);
            S1[o] = h;
            S1[o + 4352] = f2bf(v - bf2f(h));
        }
    }
    gather_wfrag(S2, Wo, tid);
    __syncthreads();

    f32x4 oacc[4];
    #pragma unroll
    for (int n = 0; n < 4; ++n) oacc[n] = (f32x4){0.f, 0.f, 0.f, 0.f};
    #pragma unroll
    for (int cd = 0; cd < 2; ++cd) {
        short8 ah = xfrag(S1, orow, cd, g);
        short8 al = xfrag(S1 + 4352, orow, cd, g);
        #pragma unroll
        for (int n = 0; n < 4; ++n) {
            short8 wh = *(const short8*)&S2[WFIDX(n, cd, 0, lane)];
            short8 wl = *(const short8*)&S2[WFIDX(n, cd, 1, lane)];
            oacc[n] = MFMA_BF16(ah, wh, oacc[n], 0, 0, 0);
            oacc[n] = MFMA_BF16(al, wh, oacc[n], 0, 0, 0);
            oacc[n] = MFMA_BF16(ah, wl, oacc[n], 0, 0, 0);
        }
    }
    float* obt = out + ((size_t)b * N_ * T_ + t) * D_;
    #pragma unroll
    for (int n = 0; n < 4; ++n) {
        #pragma unroll
        for (int r = 0; r < 4; ++r) {
            float v = fmaxf(oacc[n][r] + bos[n * 16 + li], 0.f);
            obt[(size_t)(r0 + w * 16 + g * 4 + r) * rstride + n * 16 + li] = v;
        }
    }
}

extern "C" void kernel_launch(void* const* d_in, const int* in_sizes, int n_in,
                              void* d_out, int out_size, void* d_ws, size_t ws_size,
                              hipStream_t stream) {
    const float* x  = (const float*)d_in[0];
    const float* W1 = (const float*)d_in[1];
    const float* b1 = (const float*)d_in[2];
    const float* W2 = (const float*)d_in[3];
    const float* b2 = (const float*)d_in[4];
    const float* Wo = (const float*)d_in[5];
    const float* bo = (const float*)d_in[6];
    float* out = (float*)d_out;

    gcn_mfma<<<dim3(B_ * T_ * NT), dim3(256), 0, stream>>>(x, W1, b1, W2, b2, Wo, bo, out);
}

// Round 4
// 219.333 us; speedup vs baseline: 8.7428x; 1.4143x over previous
//
#include <hip/hip_runtime.h>

// DynamicGCN B=16 N=512 T=24 D=E=H=64 — two-pass MFMA transpose-chain, split-bf16.
// Per (b,t): E1=XW1+b1, E2=XW2+b2, S=relu(E1 E2^T), A=softmax(S), h=AX, out=relu(hW+b)
// Pass 1: E1/E2/XT/Wo fragments -> ws (frag-ready layouts, R3-verified repacks).
// Pass 2: 1-wave blocks, barrier-free flash loop, frags loaded straight from ws.

#define B_ 16
#define N_ 512
#define T_ 24
#define D_ 64
#define NT 8

typedef __attribute__((ext_vector_type(8))) short short8;
typedef __attribute__((ext_vector_type(4))) unsigned short u16x4;
typedef __attribute__((ext_vector_type(4))) float f32x4;

#define MFMA_BF16 __builtin_amdgcn_mfma_f32_16x16x32_bf16
#define WFIDX(q, cd, s, l) (((((q)*2 + (cd))*2 + (s))*64 + (l))*8)

// ws layout (bytes)
#define OFF_E1 0u
#define OFF_E2 50331648u          // 384*32*4*1024
#define OFF_XT 100663296u         // + same
#define OFF_WO 125829120u         // + 384*8*8*1024
#define WS_NEED 125845504u        // + 16384

__device__ __forceinline__ unsigned short f2bf(float f) {
    unsigned u = __float_as_uint(f);
    return (unsigned short)((u + 0x7FFFu + ((u >> 16) & 1u)) >> 16);
}
__device__ __forceinline__ float bf2f(unsigned short h) {
    return __uint_as_float(((unsigned)h) << 16);
}
// X-tile LDS layout (u16 element index in a 4352-elem plane):
// addr(j,d) = (d>>4)*1088 + (j>>2)*68 + (j&3)*16 + (d&15)
__device__ __forceinline__ int XIDX(int j, int d) {
    return (d >> 4) * 1088 + (j >> 2) * 68 + ((j & 3) << 4) + (d & 15);
}
__device__ __forceinline__ int XTIDX(int d, int j) {
    return (j >> 4) * 1088 + (d >> 2) * 68 + ((d & 3) << 4) + (j & 15);
}
// 32-row plane for pass-2 epilogue: rows i in [0,32), cols d in [0,64)
__device__ __forceinline__ int XIDX32(int i, int d) {
    return (d >> 4) * 544 + (i >> 2) * 68 + ((i & 3) << 4) + (d & 15);
}

// stage one 64x64 f32 tile -> bf16 hi/lo planes in XIDX layout (+ optional d-major hi twin)
__device__ __forceinline__ void stage_x(unsigned short* xb, unsigned short* xt,
                                        const float* src, int tid) {
    const int rs = T_ * D_;
    #pragma unroll
    for (int it = 0; it < 4; ++it) {
        int idx = tid + it * 256;
        int j = idx >> 4, d0 = (idx & 15) << 2;
        f32x4 v = *(const f32x4*)(src + (size_t)j * rs + d0);
        u16x4 hv, lv;
        #pragma unroll
        for (int k = 0; k < 4; ++k) {
            unsigned short h = f2bf(v[k]);
            hv[k] = h;
            lv[k] = f2bf(v[k] - bf2f(h));
        }
        int o = XIDX(j, d0);
        *(u16x4*)&xb[o] = hv;
        *(u16x4*)&xb[o + 4352] = lv;
        if (xt) {
            #pragma unroll
            for (int k = 0; k < 4; ++k)
                xt[XTIDX(d0 + k, j)] = hv[k];
        }
    }
}

// gather MFMA A/B frags of a 64x64 row-major weight (global) into LDS (hi/lo)
__device__ __forceinline__ void gather_wfrag(unsigned short* wf, const float* Wg, int tid) {
    int lane = tid & 63, w = tid >> 6;
    #pragma unroll
    for (int k = 0; k < 2; ++k) {
        int pair = w * 2 + k;
        int q = pair >> 1, cd = pair & 1;
        int col = q * 16 + (lane & 15);
        short8 hf, lf;
        #pragma unroll
        for (int jj = 0; jj < 8; ++jj) {
            int row = cd * 32 + ((jj >> 2) << 4) + ((lane >> 4) << 2) + (jj & 3);
            float v = Wg[row * 64 + col];
            unsigned short h = f2bf(v);
            hf[jj] = (short)h;
            lf[jj] = (short)f2bf(v - bf2f(h));
        }
        *(short8*)&wf[WFIDX(q, cd, 0, lane)] = hf;
        *(short8*)&wf[WFIDX(q, cd, 1, lane)] = lf;
    }
}

// row-pattern operand frag: row fixed per lane, slots jj -> col = 32*cd + lam(g,jj)
__device__ __forceinline__ short8 xfrag(const unsigned short* xb, int row, int cd, int g) {
    u16x4 a = *(const u16x4*)&xb[XIDX(row, cd * 32 + (g << 2))];
    u16x4 b = *(const u16x4*)&xb[XIDX(row, cd * 32 + 16 + (g << 2))];
    short8 r;
    r[0] = (short)a[0]; r[1] = (short)a[1]; r[2] = (short)a[2]; r[3] = (short)a[3];
    r[4] = (short)b[0]; r[5] = (short)b[1]; r[6] = (short)b[2]; r[7] = (short)b[3];
    return r;
}
__device__ __forceinline__ short8 xfrag32(const unsigned short* p, int row, int cd, int g) {
    u16x4 a = *(const u16x4*)&p[XIDX32(row, cd * 32 + (g << 2))];
    u16x4 b = *(const u16x4*)&p[XIDX32(row, cd * 32 + 16 + (g << 2))];
    short8 r;
    r[0] = (short)a[0]; r[1] = (short)a[1]; r[2] = (short)a[2]; r[3] = (short)a[3];
    r[4] = (short)b[0]; r[5] = (short)b[1]; r[6] = (short)b[2]; r[7] = (short)b[3];
    return r;
}

// C/D acc -> A/B frag repack (R3-verified) + store hi/lo to ws
__device__ __forceinline__ void repack_store(char* base, const f32x4* acc, int lane) {
    #pragma unroll
    for (int c = 0; c < 2; ++c) {
        short8 fh, fl;
        #pragma unroll
        for (int jj = 0; jj < 8; ++jj) {
            float v = acc[c * 2 + (jj >> 2)][jj & 3];
            unsigned short h = f2bf(v);
            fh[jj] = (short)h;
            fl[jj] = (short)f2bf(v - bf2f(h));
        }
        *(short8*)(base + (size_t)(c * 2 + 0) * 1024 + lane * 16) = fh;
        *(short8*)(base + (size_t)(c * 2 + 1) * 1024 + lane * 16) = fl;
    }
}

// ============================= PASS 1 =============================
__global__ __launch_bounds__(256, 2)
void gcn_pre(const float* __restrict__ x,
             const float* __restrict__ W1, const float* __restrict__ b1,
             const float* __restrict__ W2, const float* __restrict__ b2,
             const float* __restrict__ Wo, char* __restrict__ ws)
{
    __shared__ __align__(16) char smem[59648];
    unsigned short* S1  = (unsigned short*)smem;             // 17408: Xq hi/lo
    unsigned short* XT  = (unsigned short*)(smem + 17408);   // 8704: d-major hi
    unsigned short* WF1 = (unsigned short*)(smem + 26112);   // 16384
    unsigned short* WF2 = (unsigned short*)(smem + 42496);   // 16384
    float* b1s = (float*)(smem + 58880);
    float* b2s = (float*)(smem + 59136);

    const int tid = threadIdx.x;
    const int lane = tid & 63;
    const int w = tid >> 6;
    const int g = lane >> 4;
    const int li = lane & 15;

    const int bid = blockIdx.x;
    const int tile = bid & 7;
    const int bt = bid >> 3;
    const int b = bt / T_;
    const int t = bt - b * T_;
    const int r0 = tile * 64;

    const size_t rstride = (size_t)T_ * D_;
    const float* xbt = x + ((size_t)b * N_ * T_ + t) * D_;

    if (tid < 64) b1s[tid] = b1[tid];
    else if (tid < 128) b2s[tid - 64] = b2[tid - 64];

    gather_wfrag(WF1, W1, tid);
    gather_wfrag(WF2, W2, tid);
    stage_x(S1, XT, xbt + (size_t)r0 * rstride, tid);
    __syncthreads();

    // E1T and E2T for own i-group (orow), sharing the Xq fragment reads
    f32x4 e1acc[4], e2acc[4];
    #pragma unroll
    for (int q = 0; q < 4; ++q) {
        e1acc[q] = (f32x4){0.f, 0.f, 0.f, 0.f};
        e2acc[q] = (f32x4){0.f, 0.f, 0.f, 0.f};
    }
    const int orow = w * 16 + li;
    #pragma unroll
    for (int cd = 0; cd < 2; ++cd) {
        short8 xh = xfrag(S1, orow, cd, g);
        short8 xl = xfrag(S1 + 4352, orow, cd, g);
        #pragma unroll
        for (int q = 0; q < 4; ++q) {
            short8 wh = *(const short8*)&WF1[WFIDX(q, cd, 0, lane)];
            short8 wl = *(const short8*)&WF1[WFIDX(q, cd, 1, lane)];
            e1acc[q] = MFMA_BF16(wh, xh, e1acc[q], 0, 0, 0);
            e1acc[q] = MFMA_BF16(wh, xl, e1acc[q], 0, 0, 0);
            e1acc[q] = MFMA_BF16(wl, xh, e1acc[q], 0, 0, 0);
            short8 vh = *(const short8*)&WF2[WFIDX(q, cd, 0, lane)];
            short8 vl = *(const short8*)&WF2[WFIDX(q, cd, 1, lane)];
            e2acc[q] = MFMA_BF16(vh, xh, e2acc[q], 0, 0, 0);
            e2acc[q] = MFMA_BF16(vh, xl, e2acc[q], 0, 0, 0);
            e2acc[q] = MFMA_BF16(vl, xh, e2acc[q], 0, 0, 0);
        }
    }
    #pragma unroll
    for (int q = 0; q < 4; ++q) {
        #pragma unroll
        for (int r = 0; r < 4; ++r) {
            e1acc[q][r] += b1s[q * 16 + g * 4 + r];
            e2acc[q][r] += b2s[q * 16 + g * 4 + r];
        }
    }
    const int grp = bt * 32 + tile * 4 + w;     // global 16-row group index
    repack_store(ws + OFF_E1 + (size_t)grp * 4096, e1acc, lane);
    repack_store(ws + OFF_E2 + (size_t)grp * 4096, e2acc, lane);

    // XT PV B-frags (hi only): 8 frags per tile, 2 per wave
    #pragma unroll
    for (int k = 0; k < 2; ++k) {
        int idx = w * 2 + k;
        int c = idx >> 2, n = idx & 3;
        short8 f = xfrag(XT, n * 16 + li, c, g);
        *(short8*)(ws + OFF_XT + (size_t)((bt * 8 + tile) * 8 + c * 4 + n) * 1024
                   + lane * 16) = f;
    }

    // Wo frags (once, block 0)
    if (bid == 0) {
        #pragma unroll
        for (int k = 0; k < 2; ++k) {
            int pair = w * 2 + k;
            int q = pair >> 1, cd = pair & 1;
            int col = q * 16 + li;
            short8 hf, lf;
            #pragma unroll
            for (int jj = 0; jj < 8; ++jj) {
                int row = cd * 32 + ((jj >> 2) << 4) + (g << 2) + (jj & 3);
                float v = Wo[row * 64 + col];
                unsigned short h = f2bf(v);
                hf[jj] = (short)h;
                lf[jj] = (short)f2bf(v - bf2f(h));
            }
            *(short8*)(ws + OFF_WO + (size_t)((q * 2 + cd) * 2 + 0) * 1024 + lane * 16) = hf;
            *(short8*)(ws + OFF_WO + (size_t)((q * 2 + cd) * 2 + 1) * 1024 + lane * 16) = lf;
        }
    }
}

// ============================= PASS 2 =============================
__global__ __launch_bounds__(64, 3)
void gcn_attn(const char* __restrict__ ws, const float* __restrict__ bo,
              float* __restrict__ out)
{
    __shared__ __align__(16) unsigned short hplane[4352];   // 32x64 hi(2176)+lo(2176)

    const int lane = threadIdx.x;
    const int g = lane >> 4;
    const int li = lane & 15;

    // chunked XCD swizzle: keep the 16 blocks of one (b,t) on one XCD
    const int B0 = blockIdx.x;
    const int wid = (B0 & 7) * 768 + (B0 >> 3);
    const int bt = wid >> 4;
    const int iseg = wid & 15;
    const int b = bt / T_;
    const int t = bt - b * T_;

    const char* e1b = ws + OFF_E1 + (size_t)(bt * 32 + iseg * 2) * 4096;
    const char* e2b = ws + OFF_E2 + (size_t)bt * 131072;
    const char* xtb = ws + OFF_XT + (size_t)bt * 65536;

    short8 e1h[2][2], e1l[2][2];
    #pragma unroll
    for (int ig = 0; ig < 2; ++ig)
        #pragma unroll
        for (int c = 0; c < 2; ++c) {
            e1h[ig][c] = *(const short8*)(e1b + (size_t)(ig * 4 + c * 2 + 0) * 1024 + lane * 16);
            e1l[ig][c] = *(const short8*)(e1b + (size_t)(ig * 4 + c * 2 + 1) * 1024 + lane * 16);
        }

    f32x4 hacc[2][4];
    #pragma unroll
    for (int ig = 0; ig < 2; ++ig)
        #pragma unroll
        for (int n = 0; n < 4; ++n) hacc[ig][n] = (f32x4){0.f, 0.f, 0.f, 0.f};
    float m[2] = {0.f, 0.f}, l[2] = {0.f, 0.f};

    #pragma unroll 1
    for (int jc = 0; jc < 16; ++jc) {
        const char* eb = e2b + (size_t)jc * 8192;
        short8 ah[2][2], al[2][2];
        #pragma unroll
        for (int a = 0; a < 2; ++a)
            #pragma unroll
            for (int c = 0; c < 2; ++c) {
                ah[a][c] = *(const short8*)(eb + (size_t)(a * 4 + c * 2 + 0) * 1024 + lane * 16);
                al[a][c] = *(const short8*)(eb + (size_t)(a * 4 + c * 2 + 1) * 1024 + lane * 16);
            }
        short8 xt[4];
        const char* xb = xtb + (size_t)((jc >> 1) * 8 + (jc & 1) * 4) * 1024;
        #pragma unroll
        for (int n = 0; n < 4; ++n)
            xt[n] = *(const short8*)(xb + (size_t)n * 1024 + lane * 16);

        // ST = E2 E1^T (3-term split)
        f32x4 st[2][2];
        #pragma unroll
        for (int a = 0; a < 2; ++a)
            #pragma unroll
            for (int ig = 0; ig < 2; ++ig) st[a][ig] = (f32x4){0.f, 0.f, 0.f, 0.f};
        #pragma unroll
        for (int a = 0; a < 2; ++a)
            #pragma unroll
            for (int ig = 0; ig < 2; ++ig)
                #pragma unroll
                for (int c = 0; c < 2; ++c) {
                    st[a][ig] = MFMA_BF16(ah[a][c], e1h[ig][c], st[a][ig], 0, 0, 0);
                    st[a][ig] = MFMA_BF16(al[a][c], e1h[ig][c], st[a][ig], 0, 0, 0);
                    st[a][ig] = MFMA_BF16(ah[a][c], e1l[ig][c], st[a][ig], 0, 0, 0);
                }

        // relu + online softmax (defer-max THR=8)
        #pragma unroll
        for (int ig = 0; ig < 2; ++ig) {
            float tm = 0.f;
            #pragma unroll
            for (int a = 0; a < 2; ++a)
                #pragma unroll
                for (int r = 0; r < 4; ++r) {
                    float s = fmaxf(st[a][ig][r], 0.f);
                    st[a][ig][r] = s;
                    tm = fmaxf(tm, s);
                }
            tm = fmaxf(tm, __shfl_xor(tm, 16));
            tm = fmaxf(tm, __shfl_xor(tm, 32));
            if (!__all(tm - m[ig] <= 8.f)) {
                float mn = fmaxf(m[ig], tm);
                float corr = __expf(m[ig] - mn);
                m[ig] = mn;
                l[ig] *= corr;
                #pragma unroll
                for (int r = 0; r < 4; ++r) {
                    float sc = __shfl(corr, g * 4 + r);
                    #pragma unroll
                    for (int n = 0; n < 4; ++n) hacc[ig][n][r] *= sc;
                }
            }
            float ps = 0.f;
            #pragma unroll
            for (int a = 0; a < 2; ++a)
                #pragma unroll
                for (int r = 0; r < 4; ++r) {
                    float p = __expf(st[a][ig][r] - m[ig]);
                    st[a][ig][r] = p;
                    ps += p;
                }
            ps += __shfl_xor(ps, 16);
            ps += __shfl_xor(ps, 32);
            l[ig] += ps;
        }

        // PV
        #pragma unroll
        for (int ig = 0; ig < 2; ++ig) {
            short8 pa;
            #pragma unroll
            for (int jj = 0; jj < 8; ++jj)
                pa[jj] = (short)f2bf(st[jj >> 2][ig][jj & 3]);
            #pragma unroll
            for (int n = 0; n < 4; ++n)
                hacc[ig][n] = MFMA_BF16(pa, xt[n], hacc[ig][n], 0, 0, 0);
        }
    }

    // epilogue: h /= l -> hplane (hi/lo), out = relu(h Wo + bo)
    #pragma unroll
    for (int ig = 0; ig < 2; ++ig) {
        float linv = 1.0f / l[ig];
        #pragma unroll
        for (int r = 0; r < 4; ++r) {
            float lr = __shfl(linv, g * 4 + r);
            #pragma unroll
            for (int n = 0; n < 4; ++n) {
                float v = hacc[ig][n][r] * lr;
                unsigned short h = f2bf(v);
                int o = XIDX32(ig * 16 + g * 4 + r, n * 16 + li);
                hplane[o] = h;
                hplane[o + 2176] = f2bf(v - bf2f(h));
            }
        }
    }
    __syncthreads();

    f32x4 oacc[2][4];
    #pragma unroll
    for (int ig = 0; ig < 2; ++ig)
        #pragma unroll
        for (int q = 0; q < 4; ++q) oacc[ig][q] = (f32x4){0.f, 0.f, 0.f, 0.f};
    #pragma unroll
    for (int ig = 0; ig < 2; ++ig)
        #pragma unroll
        for (int cd = 0; cd < 2; ++cd) {
            short8 ahh = xfrag32(hplane, ig * 16 + li, cd, g);
            short8 alo = xfrag32(hplane + 2176, ig * 16 + li, cd, g);
            #pragma unroll
            for (int q = 0; q < 4; ++q) {
                short8 wh = *(const short8*)(ws + OFF_WO
                              + (size_t)((q * 2 + cd) * 2 + 0) * 1024 + lane * 16);
                short8 wl = *(const short8*)(ws + OFF_WO
                              + (size_t)((q * 2 + cd) * 2 + 1) * 1024 + lane * 16);
                oacc[ig][q] = MFMA_BF16(ahh, wh, oacc[ig][q], 0, 0, 0);
                oacc[ig][q] = MFMA_BF16(alo, wh, oacc[ig][q], 0, 0, 0);
                oacc[ig][q] = MFMA_BF16(ahh, wl, oacc[ig][q], 0, 0, 0);
            }
        }

    float boq[4];
    #pragma unroll
    for (int q = 0; q < 4; ++q) boq[q] = bo[q * 16 + li];

    const size_t rstride = (size_t)T_ * D_;
    float* obt = out + ((size_t)b * N_ * T_ + t) * D_;
    const int i0 = iseg * 32;
    #pragma unroll
    for (int ig = 0; ig < 2; ++ig)
        #pragma unroll
        for (int q = 0; q < 4; ++q)
            #pragma unroll
            for (int r = 0; r < 4; ++r) {
                float v = fmaxf(oacc[ig][q][r] + boq[q], 0.f);
                obt[(size_t)(i0 + ig * 16 + g * 4 + r) * rstride + q * 16 + li] = v;
            }
}

// ==================== FALLBACK (R3, verified) =====================
__global__ __launch_bounds__(256, 2)
void gcn_mfma(const float* __restrict__ x,
              const float* __restrict__ W1, const float* __restrict__ b1,
              const float* __restrict__ W2, const float* __restrict__ b2,
              const float* __restrict__ Wo, const float* __restrict__ bo,
              float* __restrict__ out)
{
    __shared__ __align__(16) char smem[60672];
    unsigned short* S1 = (unsigned short*)smem;
    unsigned short* S2 = (unsigned short*)(smem + 17408);
    unsigned short* XT = (unsigned short*)(smem + 34816);
    unsigned short* SH = (unsigned short*)(smem + 43520);
    float* b1s = (float*)(smem + 59904);
    float* b2s = (float*)(smem + 60160);
    float* bos = (float*)(smem + 60416);

    const int tid = threadIdx.x;
    const int lane = tid & 63;
    const int w = tid >> 6;
    const int g = lane >> 4;
    const int li = lane & 15;

    const int bid = blockIdx.x;
    const int tile = bid & (NT - 1);
    const int bt = bid >> 3;
    const int b = bt / T_;
    const int t = bt - b * T_;
    const int r0 = tile * 64;

    const size_t rstride = (size_t)T_ * D_;
    const float* xbt = x + ((size_t)b * N_ * T_ + t) * D_;

    if (tid < 64) b1s[tid] = b1[tid];
    else if (tid < 128) b2s[tid - 64] = b2[tid - 64];
    else if (tid < 192) bos[tid - 128] = bo[tid - 128];

    gather_wfrag(S2, W1, tid);
    stage_x(S1, nullptr, xbt + (size_t)r0 * rstride, tid);
    __syncthreads();

    f32x4 eacc[4];
    #pragma unroll
    for (int q = 0; q < 4; ++q) eacc[q] = (f32x4){0.f, 0.f, 0.f, 0.f};
    const int orow = w * 16 + li;
    #pragma unroll
    for (int cd = 0; cd < 2; ++cd) {
        short8 xh = xfrag(S1, orow, cd, g);
        short8 xl = xfrag(S1 + 4352, orow, cd, g);
        #pragma unroll
        for (int q = 0; q < 4; ++q) {
            short8 wh = *(const short8*)&S2[WFIDX(q, cd, 0, lane)];
            short8 wl = *(const short8*)&S2[WFIDX(q, cd, 1, lane)];
            eacc[q] = MFMA_BF16(wh, xh, eacc[q], 0, 0, 0);
            eacc[q] = MFMA_BF16(wh, xl, eacc[q], 0, 0, 0);
            eacc[q] = MFMA_BF16(wl, xh, eacc[q], 0, 0, 0);
        }
    }
    short8 e1h[2], e1l[2];
    #pragma unroll
    for (int q = 0; q < 4; ++q) {
        #pragma unroll
        for (int r = 0; r < 4; ++r) eacc[q][r] += b1s[q * 16 + g * 4 + r];
    }
    #pragma unroll
    for (int c = 0; c < 2; ++c) {
        #pragma unroll
        for (int jj = 0; jj < 8; ++jj) {
            float v = eacc[c * 2 + (jj >> 2)][jj & 3];
            unsigned short h = f2bf(v);
            e1h[c][jj] = (short)h;
            e1l[c][jj] = (short)f2bf(v - bf2f(h));
        }
    }
    __syncthreads();
    gather_wfrag(S1, W2, tid);

    f32x4 hacc[4];
    #pragma unroll
    for (int n = 0; n < 4; ++n) hacc[n] = (f32x4){0.f, 0.f, 0.f, 0.f};
    float mrun = 0.f, lsum = 0.f;

    #pragma unroll 1
    for (int jt8 = 0; jt8 < NT; ++jt8) {
        __syncthreads();
        stage_x(S2, XT, xbt + (size_t)(jt8 * 64) * rstride, tid);
        __syncthreads();

        f32x4 e2[4];
        #pragma unroll
        for (int q = 0; q < 4; ++q) e2[q] = (f32x4){0.f, 0.f, 0.f, 0.f};
        #pragma unroll
        for (int cd = 0; cd < 2; ++cd) {
            short8 xh = xfrag(S2, orow, cd, g);
            short8 xl = xfrag(S2 + 4352, orow, cd, g);
            #pragma unroll
            for (int q = 0; q < 4; ++q) {
                short8 wh = *(const short8*)&S1[WFIDX(q, cd, 0, lane)];
                short8 wl = *(const short8*)&S1[WFIDX(q, cd, 1, lane)];
                e2[q] = MFMA_BF16(wh, xh, e2[q], 0, 0, 0);
                e2[q] = MFMA_BF16(wh, xl, e2[q], 0, 0, 0);
                e2[q] = MFMA_BF16(wl, xh, e2[q], 0, 0, 0);
            }
        }
        #pragma unroll
        for (int q = 0; q < 4; ++q) {
            #pragma unroll
            for (int r = 0; r < 4; ++r) e2[q][r] += b2s[q * 16 + g * 4 + r];
        }
        #pragma unroll
        for (int c = 0; c < 2; ++c) {
            short8 fh, fl;
            #pragma unroll
            for (int jj = 0; jj < 8; ++jj) {
                float v = e2[c * 2 + (jj >> 2)][jj & 3];
                unsigned short h = f2bf(v);
                fh[jj] = (short)h;
                fl[jj] = (short)f2bf(v - bf2f(h));
            }
            *(short8*)&SH[WFIDX(w, c, 0, lane)] = fh;
            *(short8*)&SH[WFIDX(w, c, 1, lane)] = fl;
        }
        __syncthreads();

        f32x4 st[4];
        #pragma unroll
        for (int jt = 0; jt < 4; ++jt) st[jt] = (f32x4){0.f, 0.f, 0.f, 0.f};
        #pragma unroll
        for (int jt = 0; jt < 4; ++jt) {
            #pragma unroll
            for (int c = 0; c < 2; ++c) {
                short8 ah = *(const short8*)&SH[WFIDX(jt, c, 0, lane)];
                short8 al = *(const short8*)&SH[WFIDX(jt, c, 1, lane)];
                st[jt] = MFMA_BF16(ah, e1h[c], st[jt], 0, 0, 0);
                st[jt] = MFMA_BF16(ah, e1l[c], st[jt], 0, 0, 0);
                st[jt] = MFMA_BF16(al, e1h[c], st[jt], 0, 0, 0);
            }
        }
        float tm = 0.f;
        #pragma unroll
        for (int jt = 0; jt < 4; ++jt) {
            #pragma unroll
            for (int r = 0; r < 4; ++r) {
                float s = fmaxf(st[jt][r], 0.f);
                st[jt][r] = s;
                tm = fmaxf(tm, s);
            }
        }
        tm = fmaxf(tm, __shfl_xor(tm, 16));
        tm = fmaxf(tm, __shfl_xor(tm, 32));
        float mn = fmaxf(mrun, tm);
        float corr = __expf(mrun - mn);
        float ps = 0.f;
        #pragma unroll
        for (int jt = 0; jt < 4; ++jt) {
            #pragma unroll
            for (int r = 0; r < 4; ++r) {
                float p = __expf(st[jt][r] - mn);
                st[jt][r] = p;
                ps += p;
            }
        }
        ps += __shfl_xor(ps, 16);
        ps += __shfl_xor(ps, 32);
        lsum = lsum * corr + ps;
        mrun = mn;
        float sc0 = __shfl(corr, g * 4 + 0);
        float sc1 = __shfl(corr, g * 4 + 1);
        float sc2 = __shfl(corr, g * 4 + 2);
        float sc3 = __shfl(corr, g * 4 + 3);
        #pragma unroll
        for (int n = 0; n < 4; ++n) {
            hacc[n][0] *= sc0; hacc[n][1] *= sc1; hacc[n][2] *= sc2; hacc[n][3] *= sc3;
        }

        #pragma unroll
        for (int c = 0; c < 2; ++c) {
            short8 pa;
            #pragma unroll
            for (int jj = 0; jj < 8; ++jj)
                pa[jj] = (short)f2bf(st[c * 2 + (jj >> 2)][jj & 3]);
            #pragma unroll
            for (int n = 0; n < 4; ++n) {
                short8 xb = xfrag(XT, n * 16 + li, c, g);
                hacc[n] = MFMA_BF16(pa, xb, hacc[n], 0, 0, 0);
            }
        }
    }

    float linv = 1.0f / lsum;
    float l0 = __shfl(linv, g * 4 + 0);
    float l1 = __shfl(linv, g * 4 + 1);
    float l2 = __shfl(linv, g * 4 + 2);
    float l3 = __shfl(linv, g * 4 + 3);
    __syncthreads();
    #pragma unroll
    for (int n = 0; n < 4; ++n) {
        float lr[4] = {l0, l1, l2, l3};
        #pragma unroll
        for (int r = 0; r < 4; ++r) {
            float v = hacc[n][r] * lr[r];
            unsigned short h = f2bf(v);
            int o = XIDX(w * 16 + g * 4 + r, n * 16 + li);
            S1[o] = h;
            S1[o + 4352] = f2bf(v - bf2f(h));
        }
    }
    gather_wfrag(S2, Wo, tid);
    __syncthreads();

    f32x4 oacc[4];
    #pragma unroll
    for (int n = 0; n < 4; ++n) oacc[n] = (f32x4){0.f, 0.f, 0.f, 0.f};
    #pragma unroll
    for (int cd = 0; cd < 2; ++cd) {
        short8 ah = xfrag(S1, orow, cd, g);
        short8 al = xfrag(S1 + 4352, orow, cd, g);
        #pragma unroll
        for (int n = 0; n < 4; ++n) {
            short8 wh = *(const short8*)&S2[WFIDX(n, cd, 0, lane)];
            short8 wl = *(const short8*)&S2[WFIDX(n, cd, 1, lane)];
            oacc[n] = MFMA_BF16(ah, wh, oacc[n], 0, 0, 0);
            oacc[n] = MFMA_BF16(al, wh, oacc[n], 0, 0, 0);
            oacc[n] = MFMA_BF16(ah, wl, oacc[n], 0, 0, 0);
        }
    }
    float* obt = out + ((size_t)b * N_ * T_ + t) * D_;
    #pragma unroll
    for (int n = 0; n < 4; ++n) {
        #pragma unroll
        for (int r = 0; r < 4; ++r) {
            float v = fmaxf(oacc[n][r] + bos[n * 16 + li], 0.f);
            obt[(size_t)(r0 + w * 16 + g * 4 + r) * rstride + n * 16 + li] = v;
        }
    }
}

extern "C" void kernel_launch(void* const* d_in, const int* in_sizes, int n_in,
                              void* d_out, int out_size, void* d_ws, size_t ws_size,
                              hipStream_t stream) {
    const float* x  = (const float*)d_in[0];
    const float* W1 = (const float*)d_in[1];
    const float* b1 = (const float*)d_in[2];
    const float* W2 = (const float*)d_in[3];
    const float* b2 = (const float*)d_in[4];
    const float* Wo = (const float*)d_in[5];
    const float* bo = (const float*)d_in[6];
    float* out = (float*)d_out;

    if (ws_size >= (size_t)WS_NEED) {
        char* ws = (char*)d_ws;
        gcn_pre<<<dim3(B_ * T_ * NT), dim3(256), 0, stream>>>(x, W1, b1, W2, b2, Wo, ws);
        gcn_attn<<<dim3(B_ * T_ * 16), dim3(64), 0, stream>>>(ws, bo, out);
    } else {
        gcn_mfma<<<dim3(B_ * T_ * NT), dim3(256), 0, stream>>>(x, W1, b1, W2, b2, Wo, bo, out);
    }
}

// Round 5
// 215.690 us; speedup vs baseline: 8.8905x; 1.0169x over previous
//
#include <hip/hip_runtime.h>

// DynamicGCN B=16 N=512 T=24 D=E=H=64 — three-pass MFMA transpose-chain, split-bf16.
// Per (b,t): E1=XW1+b1, E2=XW2+b2, S=relu(E1 E2^T), A=softmax(S), h=AX, out=relu(hW+b)
// wf:  weight MFMA fragments -> ws (once).
// pre: E1(*log2e)/E2/XT fragments -> ws.
// attn: 2-wave blocks, barrier-free flash loop in exp2 domain.

#define B_ 16
#define N_ 512
#define T_ 24
#define D_ 64
#define NT 8
#define LOG2E 1.44269504088896f

typedef __attribute__((ext_vector_type(8))) short short8;
typedef __attribute__((ext_vector_type(4))) unsigned short u16x4;
typedef __attribute__((ext_vector_type(4))) float f32x4;

#define MFMA_BF16 __builtin_amdgcn_mfma_f32_16x16x32_bf16
#define WFIDX(q, cd, s, l) (((((q)*2 + (cd))*2 + (s))*64 + (l))*8)

// ws layout (bytes)
#define OFF_E1 0u
#define OFF_E2 50331648u          // 384*32*4096
#define OFF_XT 100663296u         // + same
#define OFF_W1F 125829120u       // + 384*8*8*1024
#define OFF_W2F 125845504u
#define OFF_WOF 125861888u
#define WS_NEED 125878272u

__device__ __forceinline__ unsigned short f2bf(float f) {
    unsigned u = __float_as_uint(f);
    return (unsigned short)((u + 0x7FFFu + ((u >> 16) & 1u)) >> 16);
}
__device__ __forceinline__ float bf2f(unsigned short h) {
    return __uint_as_float(((unsigned)h) << 16);
}
// X-tile LDS layout (u16 element index in a 4352-elem plane):
// addr(j,d) = (d>>4)*1088 + (j>>2)*68 + (j&3)*16 + (d&15)
__device__ __forceinline__ int XIDX(int j, int d) {
    return (d >> 4) * 1088 + (j >> 2) * 68 + ((j & 3) << 4) + (d & 15);
}
__device__ __forceinline__ int XTIDX(int d, int j) {
    return (j >> 4) * 1088 + (d >> 2) * 68 + ((d & 3) << 4) + (j & 15);
}
// 32-row plane for attn epilogue
__device__ __forceinline__ int XIDX32(int i, int d) {
    return (d >> 4) * 544 + (i >> 2) * 68 + ((i & 3) << 4) + (d & 15);
}

__device__ __forceinline__ void stage_x(unsigned short* xb, unsigned short* xt,
                                        const float* src, int tid) {
    const int rs = T_ * D_;
    #pragma unroll
    for (int it = 0; it < 4; ++it) {
        int idx = tid + it * 256;
        int j = idx >> 4, d0 = (idx & 15) << 2;
        f32x4 v = *(const f32x4*)(src + (size_t)j * rs + d0);
        u16x4 hv, lv;
        #pragma unroll
        for (int k = 0; k < 4; ++k) {
            unsigned short h = f2bf(v[k]);
            hv[k] = h;
            lv[k] = f2bf(v[k] - bf2f(h));
        }
        int o = XIDX(j, d0);
        *(u16x4*)&xb[o] = hv;
        *(u16x4*)&xb[o + 4352] = lv;
        if (xt) {
            #pragma unroll
            for (int k = 0; k < 4; ++k)
                xt[XTIDX(d0 + k, j)] = hv[k];
        }
    }
}

// (used by fallback only) gather MFMA A/B frags of a 64x64 weight into LDS
__device__ __forceinline__ void gather_wfrag(unsigned short* wf, const float* Wg, int tid) {
    int lane = tid & 63, w = tid >> 6;
    #pragma unroll
    for (int k = 0; k < 2; ++k) {
        int pair = w * 2 + k;
        int q = pair >> 1, cd = pair & 1;
        int col = q * 16 + (lane & 15);
        short8 hf, lf;
        #pragma unroll
        for (int jj = 0; jj < 8; ++jj) {
            int row = cd * 32 + ((jj >> 2) << 4) + ((lane >> 4) << 2) + (jj & 3);
            float v = Wg[row * 64 + col];
            unsigned short h = f2bf(v);
            hf[jj] = (short)h;
            lf[jj] = (short)f2bf(v - bf2f(h));
        }
        *(short8*)&wf[WFIDX(q, cd, 0, lane)] = hf;
        *(short8*)&wf[WFIDX(q, cd, 1, lane)] = lf;
    }
}

__device__ __forceinline__ short8 xfrag(const unsigned short* xb, int row, int cd, int g) {
    u16x4 a = *(const u16x4*)&xb[XIDX(row, cd * 32 + (g << 2))];
    u16x4 b = *(const u16x4*)&xb[XIDX(row, cd * 32 + 16 + (g << 2))];
    short8 r;
    r[0] = (short)a[0]; r[1] = (short)a[1]; r[2] = (short)a[2]; r[3] = (short)a[3];
    r[4] = (short)b[0]; r[5] = (short)b[1]; r[6] = (short)b[2]; r[7] = (short)b[3];
    return r;
}
__device__ __forceinline__ short8 xfrag32(const unsigned short* p, int row, int cd, int g) {
    u16x4 a = *(const u16x4*)&p[XIDX32(row, cd * 32 + (g << 2))];
    u16x4 b = *(const u16x4*)&p[XIDX32(row, cd * 32 + 16 + (g << 2))];
    short8 r;
    r[0] = (short)a[0]; r[1] = (short)a[1]; r[2] = (short)a[2]; r[3] = (short)a[3];
    r[4] = (short)b[0]; r[5] = (short)b[1]; r[6] = (short)b[2]; r[7] = (short)b[3];
    return r;
}

// C/D acc -> A/B frag repack + store hi/lo to ws
__device__ __forceinline__ void repack_store(char* base, const f32x4* acc, int lane) {
    #pragma unroll
    for (int c = 0; c < 2; ++c) {
        short8 fh, fl;
        #pragma unroll
        for (int jj = 0; jj < 8; ++jj) {
            float v = acc[c * 2 + (jj >> 2)][jj & 3];
            unsigned short h = f2bf(v);
            fh[jj] = (short)h;
            fl[jj] = (short)f2bf(v - bf2f(h));
        }
        *(short8*)(base + (size_t)(c * 2 + 0) * 1024 + lane * 16) = fh;
        *(short8*)(base + (size_t)(c * 2 + 1) * 1024 + lane * 16) = fl;
    }
}

// ============================= PASS 0: weight frags =============================
__global__ __launch_bounds__(256, 1)
void gcn_wf(const float* __restrict__ W1, const float* __restrict__ W2,
            const float* __restrict__ Wo, char* __restrict__ ws)
{
    const int lane = threadIdx.x & 63;
    const int w = threadIdx.x >> 6;
    const float* Wg = (blockIdx.x == 0) ? W1 : (blockIdx.x == 1) ? W2 : Wo;
    char* dst = ws + ((blockIdx.x == 0) ? OFF_W1F : (blockIdx.x == 1) ? OFF_W2F : OFF_WOF);
    #pragma unroll
    for (int k = 0; k < 2; ++k) {
        int pair = w * 2 + k;
        int q = pair >> 1, cd = pair & 1;
        int col = q * 16 + (lane & 15);
        short8 hf, lf;
        #pragma unroll
        for (int jj = 0; jj < 8; ++jj) {
            int row = cd * 32 + ((jj >> 2) << 4) + ((lane >> 4) << 2) + (jj & 3);
            float v = Wg[row * 64 + col];
            unsigned short h = f2bf(v);
            hf[jj] = (short)h;
            lf[jj] = (short)f2bf(v - bf2f(h));
        }
        *(short8*)(dst + (size_t)(pair * 2 + 0) * 1024 + lane * 16) = hf;
        *(short8*)(dst + (size_t)(pair * 2 + 1) * 1024 + lane * 16) = lf;
    }
}

// ============================= PASS 1 =============================
__global__ __launch_bounds__(256, 2)
void gcn_pre(const float* __restrict__ x,
             const float* __restrict__ b1, const float* __restrict__ b2,
             char* __restrict__ ws)
{
    __shared__ __align__(16) char smem[26624];
    unsigned short* S1 = (unsigned short*)smem;             // 17408: Xq hi/lo
    unsigned short* XT = (unsigned short*)(smem + 17408);   // 8704: d-major hi
    float* b1s = (float*)(smem + 26112);
    float* b2s = (float*)(smem + 26368);

    const int tid = threadIdx.x;
    const int lane = tid & 63;
    const int w = tid >> 6;
    const int g = lane >> 4;
    const int li = lane & 15;

    const int bid = blockIdx.x;
    const int tile = bid & 7;
    const int bt = bid >> 3;
    const int b = bt / T_;
    const int t = bt - b * T_;
    const int r0 = tile * 64;

    const size_t rstride = (size_t)T_ * D_;
    const float* xbt = x + ((size_t)b * N_ * T_ + t) * D_;

    if (tid < 64) b1s[tid] = b1[tid];
    else if (tid < 128) b2s[tid - 64] = b2[tid - 64];

    stage_x(S1, XT, xbt + (size_t)r0 * rstride, tid);
    __syncthreads();

    const char* w1f = ws + OFF_W1F;
    const char* w2f = ws + OFF_W2F;

    f32x4 e1acc[4], e2acc[4];
    #pragma unroll
    for (int q = 0; q < 4; ++q) {
        e1acc[q] = (f32x4){0.f, 0.f, 0.f, 0.f};
        e2acc[q] = (f32x4){0.f, 0.f, 0.f, 0.f};
    }
    const int orow = w * 16 + li;
    #pragma unroll
    for (int cd = 0; cd < 2; ++cd) {
        short8 xh = xfrag(S1, orow, cd, g);
        short8 xl = xfrag(S1 + 4352, orow, cd, g);
        #pragma unroll
        for (int q = 0; q < 4; ++q) {
            size_t fo = (size_t)((q * 2 + cd) * 2) * 1024 + lane * 16;
            short8 wh = *(const short8*)(w1f + fo);
            short8 wl = *(const short8*)(w1f + fo + 1024);
            e1acc[q] = MFMA_BF16(wh, xh, e1acc[q], 0, 0, 0);
            e1acc[q] = MFMA_BF16(wh, xl, e1acc[q], 0, 0, 0);
            e1acc[q] = MFMA_BF16(wl, xh, e1acc[q], 0, 0, 0);
            short8 vh = *(const short8*)(w2f + fo);
            short8 vl = *(const short8*)(w2f + fo + 1024);
            e2acc[q] = MFMA_BF16(vh, xh, e2acc[q], 0, 0, 0);
            e2acc[q] = MFMA_BF16(vh, xl, e2acc[q], 0, 0, 0);
            e2acc[q] = MFMA_BF16(vl, xh, e2acc[q], 0, 0, 0);
        }
    }
    #pragma unroll
    for (int q = 0; q < 4; ++q) {
        #pragma unroll
        for (int r = 0; r < 4; ++r) {
            e1acc[q][r] = (e1acc[q][r] + b1s[q * 16 + g * 4 + r]) * LOG2E;  // exp2 domain
            e2acc[q][r] += b2s[q * 16 + g * 4 + r];
        }
    }
    const int grp = bt * 32 + tile * 4 + w;
    repack_store(ws + OFF_E1 + (size_t)grp * 4096, e1acc, lane);
    repack_store(ws + OFF_E2 + (size_t)grp * 4096, e2acc, lane);

    // XT PV B-frags (hi only): 8 per tile, 2 per wave
    #pragma unroll
    for (int k = 0; k < 2; ++k) {
        int idx = w * 2 + k;
        int c = idx >> 2, n = idx & 3;
        short8 f = xfrag(XT, n * 16 + li, c, g);
        *(short8*)(ws + OFF_XT + (size_t)((bt * 8 + tile) * 8 + c * 4 + n) * 1024
                   + lane * 16) = f;
    }
}

// ============================= PASS 2 =============================
__global__ __launch_bounds__(128, 3)
void gcn_attn(const char* __restrict__ ws, const float* __restrict__ bo,
              float* __restrict__ out)
{
    __shared__ __align__(16) unsigned short hplane[8704];   // 2 waves x 4352

    const int tid = threadIdx.x;
    const int lane = tid & 63;
    const int w = tid >> 6;
    const int g = lane >> 4;
    const int li = lane & 15;

    // bijective chunked XCD swizzle: 8 blocks of one (b,t) contiguous per XCD
    const int B0 = blockIdx.x;
    const int wid = (B0 & 7) * 384 + (B0 >> 3);
    const int bt = wid >> 3;
    const int iseg = (wid & 7) * 2 + w;
    const int b = bt / T_;
    const int t = bt - b * T_;

    const char* e1b = ws + OFF_E1 + (size_t)(bt * 32 + iseg * 2) * 4096;
    const char* e2b = ws + OFF_E2 + (size_t)bt * 131072;
    const char* xtb = ws + OFF_XT + (size_t)bt * 65536;

    short8 e1h[2][2], e1l[2][2];
    #pragma unroll
    for (int ig = 0; ig < 2; ++ig)
        #pragma unroll
        for (int c = 0; c < 2; ++c) {
            e1h[ig][c] = *(const short8*)(e1b + (size_t)(ig * 4 + c * 2 + 0) * 1024 + lane * 16);
            e1l[ig][c] = *(const short8*)(e1b + (size_t)(ig * 4 + c * 2 + 1) * 1024 + lane * 16);
        }

    f32x4 hacc[2][4];
    #pragma unroll
    for (int ig = 0; ig < 2; ++ig)
        #pragma unroll
        for (int n = 0; n < 4; ++n) hacc[ig][n] = (f32x4){0.f, 0.f, 0.f, 0.f};
    float m0 = 0.f, m1 = 0.f, l0 = 0.f, l1 = 0.f;

    #pragma unroll 1
    for (int jc = 0; jc < 16; ++jc) {
        const char* eb = e2b + (size_t)jc * 8192;
        const char* xb = xtb + (size_t)jc * 4096;
        short8 ah[2][2], al[2][2];
        #pragma unroll
        for (int a = 0; a < 2; ++a)
            #pragma unroll
            for (int c = 0; c < 2; ++c) {
                ah[a][c] = *(const short8*)(eb + (size_t)(a * 4 + c * 2 + 0) * 1024 + lane * 16);
                al[a][c] = *(const short8*)(eb + (size_t)(a * 4 + c * 2 + 1) * 1024 + lane * 16);
            }
        short8 xt[4];
        #pragma unroll
        for (int n = 0; n < 4; ++n)
            xt[n] = *(const short8*)(xb + (size_t)n * 1024 + lane * 16);

        // ST' = log2e * (E2 E1^T), 3-term split
        f32x4 st[2][2];
        #pragma unroll
        for (int a = 0; a < 2; ++a)
            #pragma unroll
            for (int ig = 0; ig < 2; ++ig) st[a][ig] = (f32x4){0.f, 0.f, 0.f, 0.f};
        __builtin_amdgcn_s_setprio(1);
        #pragma unroll
        for (int a = 0; a < 2; ++a)
            #pragma unroll
            for (int ig = 0; ig < 2; ++ig)
                #pragma unroll
                for (int c = 0; c < 2; ++c) {
                    st[a][ig] = MFMA_BF16(ah[a][c], e1h[ig][c], st[a][ig], 0, 0, 0);
                    st[a][ig] = MFMA_BF16(al[a][c], e1h[ig][c], st[a][ig], 0, 0, 0);
                    st[a][ig] = MFMA_BF16(ah[a][c], e1l[ig][c], st[a][ig], 0, 0, 0);
                }
        __builtin_amdgcn_s_setprio(0);

        // relu + fused dual-ig online softmax (exp2 domain, defer-max THR=8*log2e)
        float tm0 = 0.f, tm1 = 0.f;
        #pragma unroll
        for (int a = 0; a < 2; ++a)
            #pragma unroll
            for (int r = 0; r < 4; ++r) {
                float s0 = fmaxf(st[a][0][r], 0.f);
                float s1 = fmaxf(st[a][1][r], 0.f);
                st[a][0][r] = s0; st[a][1][r] = s1;
                tm0 = fmaxf(tm0, s0); tm1 = fmaxf(tm1, s1);
            }
        float u0 = __shfl_xor(tm0, 16), u1 = __shfl_xor(tm1, 16);
        tm0 = fmaxf(tm0, u0); tm1 = fmaxf(tm1, u1);
        u0 = __shfl_xor(tm0, 32); u1 = __shfl_xor(tm1, 32);
        tm0 = fmaxf(tm0, u0); tm1 = fmaxf(tm1, u1);
        bool ok = (tm0 - m0 <= 11.54f) && (tm1 - m1 <= 11.54f);
        if (!__all(ok)) {
            float mn0 = fmaxf(m0, tm0), mn1 = fmaxf(m1, tm1);
            float c0 = exp2f(m0 - mn0), c1 = exp2f(m1 - mn1);
            m0 = mn0; m1 = mn1; l0 *= c0; l1 *= c1;
            #pragma unroll
            for (int r = 0; r < 4; ++r) {
                float sc0 = __shfl(c0, g * 4 + r);
                float sc1 = __shfl(c1, g * 4 + r);
                #pragma unroll
                for (int n = 0; n < 4; ++n) {
                    hacc[0][n][r] *= sc0;
                    hacc[1][n][r] *= sc1;
                }
            }
        }
        float ps0 = 0.f, ps1 = 0.f;
        #pragma unroll
        for (int a = 0; a < 2; ++a)
            #pragma unroll
            for (int r = 0; r < 4; ++r) {
                float p0 = exp2f(st[a][0][r] - m0);
                float p1 = exp2f(st[a][1][r] - m1);
                st[a][0][r] = p0; st[a][1][r] = p1;
                ps0 += p0; ps1 += p1;
            }
        ps0 += __shfl_xor(ps0, 16); ps1 += __shfl_xor(ps1, 16);
        ps0 += __shfl_xor(ps0, 32); ps1 += __shfl_xor(ps1, 32);
        l0 += ps0; l1 += ps1;

        // PV (P packed by truncation: P >= 0)
        __builtin_amdgcn_s_setprio(1);
        #pragma unroll
        for (int ig = 0; ig < 2; ++ig) {
            short8 pa;
            #pragma unroll
            for (int jj = 0; jj < 8; ++jj)
                pa[jj] = (short)(__float_as_uint(st[jj >> 2][ig][jj & 3]) >> 16);
            #pragma unroll
            for (int n = 0; n < 4; ++n)
                hacc[ig][n] = MFMA_BF16(pa, xt[n], hacc[ig][n], 0, 0, 0);
        }
        __builtin_amdgcn_s_setprio(0);
    }

    // epilogue: h /= l -> per-wave hplane slice (hi/lo), out = relu(h Wo + bo)
    unsigned short* hp = hplane + w * 4352;
    float li0 = 1.0f / l0, li1 = 1.0f / l1;
    #pragma unroll
    for (int r = 0; r < 4; ++r) {
        float lr0 = __shfl(li0, g * 4 + r);
        float lr1 = __shfl(li1, g * 4 + r);
        #pragma unroll
        for (int n = 0; n < 4; ++n) {
            float v0 = hacc[0][n][r] * lr0;
            float v1 = hacc[1][n][r] * lr1;
            unsigned short h0 = f2bf(v0), h1 = f2bf(v1);
            int o0 = XIDX32(g * 4 + r, n * 16 + li);
            int o1 = XIDX32(16 + g * 4 + r, n * 16 + li);
            hp[o0] = h0; hp[o0 + 2176] = f2bf(v0 - bf2f(h0));
            hp[o1] = h1; hp[o1 + 2176] = f2bf(v1 - bf2f(h1));
        }
    }
    __syncthreads();

    f32x4 oacc[2][4];
    #pragma unroll
    for (int ig = 0; ig < 2; ++ig)
        #pragma unroll
        for (int q = 0; q < 4; ++q) oacc[ig][q] = (f32x4){0.f, 0.f, 0.f, 0.f};
    #pragma unroll
    for (int ig = 0; ig < 2; ++ig)
        #pragma unroll
        for (int cd = 0; cd < 2; ++cd) {
            short8 ahh = xfrag32(hp, ig * 16 + li, cd, g);
            short8 alo = xfrag32(hp + 2176, ig * 16 + li, cd, g);
            #pragma unroll
            for (int q = 0; q < 4; ++q) {
                short8 wh = *(const short8*)(ws + OFF_WOF
                              + (size_t)((q * 2 + cd) * 2 + 0) * 1024 + lane * 16);
                short8 wl = *(const short8*)(ws + OFF_WOF
                              + (size_t)((q * 2 + cd) * 2 + 1) * 1024 + lane * 16);
                oacc[ig][q] = MFMA_BF16(ahh, wh, oacc[ig][q], 0, 0, 0);
                oacc[ig][q] = MFMA_BF16(alo, wh, oacc[ig][q], 0, 0, 0);
                oacc[ig][q] = MFMA_BF16(ahh, wl, oacc[ig][q], 0, 0, 0);
            }
        }

    float boq[4];
    #pragma unroll
    for (int q = 0; q < 4; ++q) boq[q] = bo[q * 16 + li];

    const size_t rstride = (size_t)T_ * D_;
    float* obt = out + ((size_t)b * N_ * T_ + t) * D_;
    const int i0 = iseg * 32;
    #pragma unroll
    for (int ig = 0; ig < 2; ++ig)
        #pragma unroll
        for (int q = 0; q < 4; ++q)
            #pragma unroll
            for (int r = 0; r < 4; ++r) {
                float v = fmaxf(oacc[ig][q][r] + boq[q], 0.f);
                obt[(size_t)(i0 + ig * 16 + g * 4 + r) * rstride + q * 16 + li] = v;
            }
}

// ==================== FALLBACK (R3, verified) =====================
__global__ __launch_bounds__(256, 2)
void gcn_mfma(const float* __restrict__ x,
              const float* __restrict__ W1, const float* __restrict__ b1,
              const float* __restrict__ W2, const float* __restrict__ b2,
              const float* __restrict__ Wo, const float* __restrict__ bo,
              float* __restrict__ out)
{
    __shared__ __align__(16) char smem[60672];
    unsigned short* S1 = (unsigned short*)smem;
    unsigned short* S2 = (unsigned short*)(smem + 17408);
    unsigned short* XT = (unsigned short*)(smem + 34816);
    unsigned short* SH = (unsigned short*)(smem + 43520);
    float* b1s = (float*)(smem + 59904);
    float* b2s = (float*)(smem + 60160);
    float* bos = (float*)(smem + 60416);

    const int tid = threadIdx.x;
    const int lane = tid & 63;
    const int w = tid >> 6;
    const int g = lane >> 4;
    const int li = lane & 15;

    const int bid = blockIdx.x;
    const int tile = bid & (NT - 1);
    const int bt = bid >> 3;
    const int b = bt / T_;
    const int t = bt - b * T_;
    const int r0 = tile * 64;

    const size_t rstride = (size_t)T_ * D_;
    const float* xbt = x + ((size_t)b * N_ * T_ + t) * D_;

    if (tid < 64) b1s[tid] = b1[tid];
    else if (tid < 128) b2s[tid - 64] = b2[tid - 64];
    else if (tid < 192) bos[tid - 128] = bo[tid - 128];

    gather_wfrag(S2, W1, tid);
    stage_x(S1, nullptr, xbt + (size_t)r0 * rstride, tid);
    __syncthreads();

    f32x4 eacc[4];
    #pragma unroll
    for (int q = 0; q < 4; ++q) eacc[q] = (f32x4){0.f, 0.f, 0.f, 0.f};
    const int orow = w * 16 + li;
    #pragma unroll
    for (int cd = 0; cd < 2; ++cd) {
        short8 xh = xfrag(S1, orow, cd, g);
        short8 xl = xfrag(S1 + 4352, orow, cd, g);
        #pragma unroll
        for (int q = 0; q < 4; ++q) {
            short8 wh = *(const short8*)&S2[WFIDX(q, cd, 0, lane)];
            short8 wl = *(const short8*)&S2[WFIDX(q, cd, 1, lane)];
            eacc[q] = MFMA_BF16(wh, xh, eacc[q], 0, 0, 0);
            eacc[q] = MFMA_BF16(wh, xl, eacc[q], 0, 0, 0);
            eacc[q] = MFMA_BF16(wl, xh, eacc[q], 0, 0, 0);
        }
    }
    short8 e1h[2], e1l[2];
    #pragma unroll
    for (int q = 0; q < 4; ++q) {
        #pragma unroll
        for (int r = 0; r < 4; ++r) eacc[q][r] += b1s[q * 16 + g * 4 + r];
    }
    #pragma unroll
    for (int c = 0; c < 2; ++c) {
        #pragma unroll
        for (int jj = 0; jj < 8; ++jj) {
            float v = eacc[c * 2 + (jj >> 2)][jj & 3];
            unsigned short h = f2bf(v);
            e1h[c][jj] = (short)h;
            e1l[c][jj] = (short)f2bf(v - bf2f(h));
        }
    }
    __syncthreads();
    gather_wfrag(S1, W2, tid);

    f32x4 hacc[4];
    #pragma unroll
    for (int n = 0; n < 4; ++n) hacc[n] = (f32x4){0.f, 0.f, 0.f, 0.f};
    float mrun = 0.f, lsum = 0.f;

    #pragma unroll 1
    for (int jt8 = 0; jt8 < NT; ++jt8) {
        __syncthreads();
        stage_x(S2, XT, xbt + (size_t)(jt8 * 64) * rstride, tid);
        __syncthreads();

        f32x4 e2[4];
        #pragma unroll
        for (int q = 0; q < 4; ++q) e2[q] = (f32x4){0.f, 0.f, 0.f, 0.f};
        #pragma unroll
        for (int cd = 0; cd < 2; ++cd) {
            short8 xh = xfrag(S2, orow, cd, g);
            short8 xl = xfrag(S2 + 4352, orow, cd, g);
            #pragma unroll
            for (int q = 0; q < 4; ++q) {
                short8 wh = *(const short8*)&S1[WFIDX(q, cd, 0, lane)];
                short8 wl = *(const short8*)&S1[WFIDX(q, cd, 1, lane)];
                e2[q] = MFMA_BF16(wh, xh, e2[q], 0, 0, 0);
                e2[q] = MFMA_BF16(wh, xl, e2[q], 0, 0, 0);
                e2[q] = MFMA_BF16(wl, xh, e2[q], 0, 0, 0);
            }
        }
        #pragma unroll
        for (int q = 0; q < 4; ++q) {
            #pragma unroll
            for (int r = 0; r < 4; ++r) e2[q][r] += b2s[q * 16 + g * 4 + r];
        }
        #pragma unroll
        for (int c = 0; c < 2; ++c) {
            short8 fh, fl;
            #pragma unroll
            for (int jj = 0; jj < 8; ++jj) {
                float v = e2[c * 2 + (jj >> 2)][jj & 3];
                unsigned short h = f2bf(v);
                fh[jj] = (short)h;
                fl[jj] = (short)f2bf(v - bf2f(h));
            }
            *(short8*)&SH[WFIDX(w, c, 0, lane)] = fh;
            *(short8*)&SH[WFIDX(w, c, 1, lane)] = fl;
        }
        __syncthreads();

        f32x4 st[4];
        #pragma unroll
        for (int jt = 0; jt < 4; ++jt) st[jt] = (f32x4){0.f, 0.f, 0.f, 0.f};
        #pragma unroll
        for (int jt = 0; jt < 4; ++jt) {
            #pragma unroll
            for (int c = 0; c < 2; ++c) {
                short8 ah = *(const short8*)&SH[WFIDX(jt, c, 0, lane)];
                short8 al = *(const short8*)&SH[WFIDX(jt, c, 1, lane)];
                st[jt] = MFMA_BF16(ah, e1h[c], st[jt], 0, 0, 0);
                st[jt] = MFMA_BF16(ah, e1l[c], st[jt], 0, 0, 0);
                st[jt] = MFMA_BF16(al, e1h[c], st[jt], 0, 0, 0);
            }
        }
        float tm = 0.f;
        #pragma unroll
        for (int jt = 0; jt < 4; ++jt) {
            #pragma unroll
            for (int r = 0; r < 4; ++r) {
                float s = fmaxf(st[jt][r], 0.f);
                st[jt][r] = s;
                tm = fmaxf(tm, s);
            }
        }
        tm = fmaxf(tm, __shfl_xor(tm, 16));
        tm = fmaxf(tm, __shfl_xor(tm, 32));
        float mn = fmaxf(mrun, tm);
        float corr = __expf(mrun - mn);
        float ps = 0.f;
        #pragma unroll
        for (int jt = 0; jt < 4; ++jt) {
            #pragma unroll
            for (int r = 0; r < 4; ++r) {
                float p = __expf(st[jt][r] - mn);
                st[jt][r] = p;
                ps += p;
            }
        }
        ps += __shfl_xor(ps, 16);
        ps += __shfl_xor(ps, 32);
        lsum = lsum * corr + ps;
        mrun = mn;
        float sc0 = __shfl(corr, g * 4 + 0);
        float sc1 = __shfl(corr, g * 4 + 1);
        float sc2 = __shfl(corr, g * 4 + 2);
        float sc3 = __shfl(corr, g * 4 + 3);
        #pragma unroll
        for (int n = 0; n < 4; ++n) {
            hacc[n][0] *= sc0; hacc[n][1] *= sc1; hacc[n][2] *= sc2; hacc[n][3] *= sc3;
        }

        #pragma unroll
        for (int c = 0; c < 2; ++c) {
            short8 pa;
            #pragma unroll
            for (int jj = 0; jj < 8; ++jj)
                pa[jj] = (short)f2bf(st[c * 2 + (jj >> 2)][jj & 3]);
            #pragma unroll
            for (int n = 0; n < 4; ++n) {
                short8 xb = xfrag(XT, n * 16 + li, c, g);
                hacc[n] = MFMA_BF16(pa, xb, hacc[n], 0, 0, 0);
            }
        }
    }

    float linv = 1.0f / lsum;
    float l0 = __shfl(linv, g * 4 + 0);
    float l1 = __shfl(linv, g * 4 + 1);
    float l2 = __shfl(linv, g * 4 + 2);
    float l3 = __shfl(linv, g * 4 + 3);
    __syncthreads();
    #pragma unroll
    for (int n = 0; n < 4; ++n) {
        float lr[4] = {l0, l1, l2, l3};
        #pragma unroll
        for (int r = 0; r < 4; ++r) {
            float v = hacc[n][r] * lr[r];
            unsigned short h = f2bf(v);
            int o = XIDX(w * 16 + g * 4 + r, n * 16 + li);
            S1[o] = h;
            S1[o + 4352] = f2bf(v - bf2f(h));
        }
    }
    gather_wfrag(S2, Wo, tid);
    __syncthreads();

    f32x4 oacc[4];
    #pragma unroll
    for (int n = 0; n < 4; ++n) oacc[n] = (f32x4){0.f, 0.f, 0.f, 0.f};
    #pragma unroll
    for (int cd = 0; cd < 2; ++cd) {
        short8 ah = xfrag(S1, orow, cd, g);
        short8 al = xfrag(S1 + 4352, orow, cd, g);
        #pragma unroll
        for (int n = 0; n < 4; ++n) {
            short8 wh = *(const short8*)&S2[WFIDX(n, cd, 0, lane)];
            short8 wl = *(const short8*)&S2[WFIDX(n, cd, 1, lane)];
            oacc[n] = MFMA_BF16(ah, wh, oacc[n], 0, 0, 0);
            oacc[n] = MFMA_BF16(al, wh, oacc[n], 0, 0, 0);
            oacc[n] = MFMA_BF16(ah, wl, oacc[n], 0, 0, 0);
        }
    }
    float* obt = out + ((size_t)b * N_ * T_ + t) * D_;
    #pragma unroll
    for (int n = 0; n < 4; ++n) {
        #pragma unroll
        for (int r = 0; r < 4; ++r) {
            float v = fmaxf(oacc[n][r] + bos[n * 16 + li], 0.f);
            obt[(size_t)(r0 + w * 16 + g * 4 + r) * rstride + n * 16 + li] = v;
        }
    }
}

extern "C" void kernel_launch(void* const* d_in, const int* in_sizes, int n_in,
                              void* d_out, int out_size, void* d_ws, size_t ws_size,
                              hipStream_t stream) {
    const float* x  = (const float*)d_in[0];
    const float* W1 = (const float*)d_in[1];
    const float* b1 = (const float*)d_in[2];
    const float* W2 = (const float*)d_in[3];
    const float* b2 = (const float*)d_in[4];
    const float* Wo = (const float*)d_in[5];
    const float* bo = (const float*)d_in[6];
    float* out = (float*)d_out;

    if (ws_size >= (size_t)WS_NEED) {
        char* ws = (char*)d_ws;
        gcn_wf<<<dim3(3), dim3(256), 0, stream>>>(W1, W2, Wo, ws);
        gcn_pre<<<dim3(B_ * T_ * NT), dim3(256), 0, stream>>>(x, b1, b2, ws);
        gcn_attn<<<dim3(B_ * T_ * NT), dim3(128), 0, stream>>>(ws, bo, out);
    } else {
        gcn_mfma<<<dim3(B_ * T_ * NT), dim3(256), 0, stream>>>(x, W1, b1, W2, b2, Wo, bo, out);
    }
}